// Round 1
// baseline (82.849 us; speedup 1.0000x reference)
//
#include <hip/hip_runtime.h>

// InfluenceEncoder: B=4096, N=257 (1 ego + 256 agents), D=16, H=128.
// One block (256 threads) per batch element.
//   phase 1: stage x[b] (257x16 fp32 = 16.4 KB) into LDS, coalesced float4.
//   phase 2: thread n computes unnormalized weight w_n; wave shfl-reduce sum.
//   phase 3: thread t -> (h = t&127, half = t>>7); W_fc[h][:] in 16 VGPRs;
//            loop 128 agents: e = relu(dot16 + b_fc[h]); acc += w_n * e.
//            All LDS reads are wave-uniform broadcasts (conflict-free).
//   phase 4: pairwise combine halves, relu -> ragg[128] in LDS.
//   phase 5: out[b,g] = dot(ragg, W_agg[g,:]) + b_agg[g], split over 2 threads.

__global__ __launch_bounds__(256) void influence_kernel(
    const float* __restrict__ x,     // [4096,257,16]
    const float* __restrict__ Wfc,   // [128,16]
    const float* __restrict__ bfc,   // [128]
    const float* __restrict__ Wagg,  // [128,128]
    const float* __restrict__ bagg,  // [128]
    float* __restrict__ out)         // [4096,128]
{
    const int b = blockIdx.x;
    const int t = threadIdx.x;

    __shared__ float xs[257 * 16];   // whole x[b], row 0 = ego
    __shared__ float wls[256];       // normalized weights
    __shared__ float red[4];         // per-wave partial sums
    __shared__ float aggp[2][128];   // half-partials (reused for final matvec)
    __shared__ float ragg[128];      // relu(agg)

    // ---- phase 1: stage x[b] ----
    {
        const float4* src = (const float4*)(x + (size_t)b * (257 * 16));
        float4* dst = (float4*)xs;
        #pragma unroll
        for (int i = 0; i < 4; ++i) dst[t + 256 * i] = src[t + 256 * i];
        if (t < 4) dst[1024 + t] = src[1024 + t];
    }
    __syncthreads();

    const float ego0 = xs[0], ego1 = xs[1];
    const float* ag = xs + 16;       // agents: 256 rows of 16

    // ---- phase 2: weights ----
    float w;
    {
        const float* a = ag + t * 16;
        const float dx = a[0] - ego0, dy = a[1] - ego1;
        w = 1.0f / (sqrtf(dx * dx + dy * dy) + 1.0f);
        if (a[6] == 1.0f) w *= 5.0f;
        float s = w;
        #pragma unroll
        for (int off = 32; off > 0; off >>= 1) s += __shfl_down(s, off);
        if ((t & 63) == 0) red[t >> 6] = s;
    }
    __syncthreads();
    {
        const float sum = red[0] + red[1] + red[2] + red[3];
        wls[t] = w / (sum + 1e-10f);
    }
    __syncthreads();

    // ---- phase 3: emb + weighted aggregation ----
    const int h = t & 127;
    const int half = t >> 7;
    float wreg[16];
    #pragma unroll
    for (int d = 0; d < 16; ++d) wreg[d] = Wfc[h * 16 + d];
    const float bh = bfc[h];

    float acc = 0.f;
    const float* ap = ag + half * (128 * 16);
    const float* wp = wls + half * 128;
    #pragma unroll 4
    for (int n = 0; n < 128; ++n) {
        const float4* a4 = (const float4*)(ap + n * 16);
        const float4 v0 = a4[0], v1 = a4[1], v2 = a4[2], v3 = a4[3];
        float e = bh;
        e = fmaf(v0.x, wreg[0], e);  e = fmaf(v0.y, wreg[1], e);
        e = fmaf(v0.z, wreg[2], e);  e = fmaf(v0.w, wreg[3], e);
        e = fmaf(v1.x, wreg[4], e);  e = fmaf(v1.y, wreg[5], e);
        e = fmaf(v1.z, wreg[6], e);  e = fmaf(v1.w, wreg[7], e);
        e = fmaf(v2.x, wreg[8], e);  e = fmaf(v2.y, wreg[9], e);
        e = fmaf(v2.z, wreg[10], e); e = fmaf(v2.w, wreg[11], e);
        e = fmaf(v3.x, wreg[12], e); e = fmaf(v3.y, wreg[13], e);
        e = fmaf(v3.z, wreg[14], e); e = fmaf(v3.w, wreg[15], e);
        e = fmaxf(e, 0.f);
        acc = fmaf(wp[n], e, acc);
    }
    aggp[half][h] = acc;
    __syncthreads();
    if (t < 128) ragg[t] = fmaxf(aggp[0][t] + aggp[1][t], 0.f);
    __syncthreads();

    // ---- phase 5: final 128x128 matvec ----
    {
        const float* wrow = Wagg + h * 128 + half * 64;
        const float* rg = ragg + half * 64;
        float o = 0.f;
        #pragma unroll
        for (int k = 0; k < 64; ++k) o = fmaf(rg[k], wrow[k], o);
        aggp[half][h] = o;
    }
    __syncthreads();
    if (t < 128) out[(size_t)b * 128 + t] = aggp[0][t] + aggp[1][t] + bagg[t];
}

extern "C" void kernel_launch(void* const* d_in, const int* in_sizes, int n_in,
                              void* d_out, int out_size, void* d_ws, size_t ws_size,
                              hipStream_t stream) {
    const float* x    = (const float*)d_in[0];
    const float* Wfc  = (const float*)d_in[1];
    const float* bfc  = (const float*)d_in[2];
    const float* Wagg = (const float*)d_in[3];
    const float* bagg = (const float*)d_in[4];
    float* out = (float*)d_out;
    influence_kernel<<<dim3(4096), dim3(256), 0, stream>>>(x, Wfc, bfc, Wagg, bagg, out);
}

// Round 2
// 38.440 us; speedup vs baseline: 2.1553x; 2.1553x over previous
//
#include <hip/hip_runtime.h>

// InfluenceEncoder via MFMA f16: B=4096, N=257, D=16, H=128.
// Kernel A (1 block/batch, 256 thr = 4 waves):
//   weights: thread n -> w_n, shfl+LDS reduce, wls[256] in LDS.
//   emb GEMM: v_mfma_f32_16x16x16_f16. Wave w owns m-tiles {4w..4w+3} x all
//   8 col-tiles. A-frag: lane reads float4 of agent row (coalesced, no LDS).
//   B-frags (Wfc) + bias preloaded in regs; bias via MFMA C-operand.
//   relu+weight+agg on D regs -> pacc[8]; shfl_xor(16,32) + LDS cross-wave
//   reduce -> relu(agg) f16 to d_ws.
// Kernel B (256 blocks x 16 batches): out = relu_agg @ Wagg^T + bagg,
//   8 K-steps of mfma_f32_16x16x16_f16, bias in C-operand.

typedef _Float16 half_t;
typedef half_t f16x4 __attribute__((ext_vector_type(4)));
typedef float f32x4 __attribute__((ext_vector_type(4)));

__global__ __launch_bounds__(256) void agg_kernel(
    const float* __restrict__ x,     // [4096,257,16]
    const float* __restrict__ Wfc,   // [128,16]
    const float* __restrict__ bfc,   // [128]
    half_t* __restrict__ agg_out)    // [4096,128] f16
{
    const int b    = blockIdx.x;
    const int t    = threadIdx.x;
    const int lane = t & 63;
    const int wv   = t >> 6;
    const int lr   = lane & 15;   // row-in-tile (A) / col-in-tile (B,D)
    const int lc   = lane >> 4;   // k-quarter / D reg-group

    __shared__ float wls[256];
    __shared__ float red[4];
    __shared__ float aggw[4][128];

    const float* xb = x + (size_t)b * (257 * 16);

    // ---- weights ----
    {
        const float2 ego = *(const float2*)xb;
        const float* ar  = xb + (t + 1) * 16;
        const float dx = ar[0] - ego.x, dy = ar[1] - ego.y;
        float w = 1.0f / (sqrtf(dx * dx + dy * dy) + 1.0f);
        if (ar[6] == 1.0f) w *= 5.0f;
        float s = w;
        #pragma unroll
        for (int off = 32; off > 0; off >>= 1) s += __shfl_down(s, off);
        if (lane == 0) red[wv] = s;
        __syncthreads();
        const float sum = red[0] + red[1] + red[2] + red[3];
        wls[t] = w / (sum + 1e-10f);
    }
    __syncthreads();

    // ---- B-frags (Wfc^T) + bias, in regs ----
    f16x4 bf[8];
    float cbias[8];
    #pragma unroll
    for (int ct = 0; ct < 8; ++ct) {
        const int col = ct * 16 + lr;
        const float4 v = *(const float4*)(Wfc + col * 16 + lc * 4);
        bf[ct] = (f16x4){(half_t)v.x, (half_t)v.y, (half_t)v.z, (half_t)v.w};
        cbias[ct] = bfc[col];
    }

    // ---- emb GEMM + relu + weighted row-agg ----
    float pacc[8] = {0.f, 0.f, 0.f, 0.f, 0.f, 0.f, 0.f, 0.f};
    #pragma unroll
    for (int i = 0; i < 4; ++i) {
        const int tm = wv * 4 + i;
        const float4 av = *(const float4*)(xb + (1 + tm * 16 + lr) * 16 + lc * 4);
        const f16x4 a = (f16x4){(half_t)av.x, (half_t)av.y, (half_t)av.z, (half_t)av.w};
        const float4 w4 = *(const float4*)(wls + tm * 16 + lc * 4);
        #pragma unroll
        for (int ct = 0; ct < 8; ++ct) {
            const f32x4 c = (f32x4){cbias[ct], cbias[ct], cbias[ct], cbias[ct]};
            const f32x4 d = __builtin_amdgcn_mfma_f32_16x16x16f16(a, bf[ct], c, 0, 0, 0);
            pacc[ct] = fmaf(w4.x, fmaxf(d[0], 0.f), pacc[ct]);
            pacc[ct] = fmaf(w4.y, fmaxf(d[1], 0.f), pacc[ct]);
            pacc[ct] = fmaf(w4.z, fmaxf(d[2], 0.f), pacc[ct]);
            pacc[ct] = fmaf(w4.w, fmaxf(d[3], 0.f), pacc[ct]);
        }
    }

    // ---- reduce across lane-groups, then across waves ----
    #pragma unroll
    for (int ct = 0; ct < 8; ++ct) {
        float p = pacc[ct];
        p += __shfl_xor(p, 16);
        p += __shfl_xor(p, 32);
        pacc[ct] = p;
    }
    if (lane < 16) {
        #pragma unroll
        for (int ct = 0; ct < 8; ++ct) aggw[wv][ct * 16 + lane] = pacc[ct];
    }
    __syncthreads();
    if (t < 128) {
        const float s = aggw[0][t] + aggw[1][t] + aggw[2][t] + aggw[3][t];
        agg_out[(size_t)b * 128 + t] = (half_t)fmaxf(s, 0.f);
    }
}

__global__ __launch_bounds__(256) void out_kernel(
    const half_t* __restrict__ agg,  // [4096,128] f16 (relu applied)
    const float* __restrict__ Wagg,  // [128,128]
    const float* __restrict__ bagg,  // [128]
    float* __restrict__ out)         // [4096,128]
{
    const int blk  = blockIdx.x;     // 16 batches per block
    const int t    = threadIdx.x;
    const int lane = t & 63;
    const int wv   = t >> 6;
    const int lr   = lane & 15;
    const int lc   = lane >> 4;
    const int row0 = blk * 16;

    f32x4 acc[2];
    #pragma unroll
    for (int ci = 0; ci < 2; ++ci) {
        const int col = (wv * 2 + ci) * 16 + lr;
        const float bb = bagg[col];
        acc[ci] = (f32x4){bb, bb, bb, bb};
    }
    #pragma unroll
    for (int kk = 0; kk < 8; ++kk) {
        const int k0 = kk * 16 + lc * 4;
        const f16x4 a = *(const f16x4*)(agg + (size_t)(row0 + lr) * 128 + k0);
        #pragma unroll
        for (int ci = 0; ci < 2; ++ci) {
            const int col = (wv * 2 + ci) * 16 + lr;
            const float4 v = *(const float4*)(Wagg + col * 128 + k0);
            const f16x4 bfr = (f16x4){(half_t)v.x, (half_t)v.y, (half_t)v.z, (half_t)v.w};
            acc[ci] = __builtin_amdgcn_mfma_f32_16x16x16f16(a, bfr, acc[ci], 0, 0, 0);
        }
    }
    #pragma unroll
    for (int ci = 0; ci < 2; ++ci) {
        const int col = (wv * 2 + ci) * 16 + lr;
        #pragma unroll
        for (int j = 0; j < 4; ++j)
            out[(size_t)(row0 + lc * 4 + j) * 128 + col] = acc[ci][j];
    }
}

extern "C" void kernel_launch(void* const* d_in, const int* in_sizes, int n_in,
                              void* d_out, int out_size, void* d_ws, size_t ws_size,
                              hipStream_t stream) {
    const float* x    = (const float*)d_in[0];
    const float* Wfc  = (const float*)d_in[1];
    const float* bfc  = (const float*)d_in[2];
    const float* Wagg = (const float*)d_in[3];
    const float* bagg = (const float*)d_in[4];
    float* out = (float*)d_out;
    half_t* agg_ws = (half_t*)d_ws;   // 4096*128 f16 = 1 MB

    agg_kernel<<<dim3(4096), dim3(256), 0, stream>>>(x, Wfc, bfc, agg_ws);
    out_kernel<<<dim3(256), dim3(256), 0, stream>>>(agg_ws, Wagg, bagg, out);
}

// Round 3
// 36.877 us; speedup vs baseline: 2.2466x; 1.0424x over previous
//
#include <hip/hip_runtime.h>

// InfluenceEncoder via MFMA f16: B=4096, N=257, D=16, H=128.
// Kernel A: wave-per-batch, barrier-free. 1024 blocks x 256 thr (4 waves);
//   wave wv handles batch b = blockIdx.x*4+wv.
//   - weights: lane l -> agents {l, l+64, l+128, l+192}; shfl_xor butterfly
//     sum; normalized w staged in wave-private LDS slice (no __syncthreads:
//     same-wave DS ops are ordered).
//   - emb GEMM: 16 m-tiles x 8 col-tiles of mfma_f32_16x16x16_f16. A-frags
//     loaded straight from global (1KB/wave coalesced), preconverted to f16.
//     Bias in MFMA C-operand. relu+weight+row-agg on D regs.
//   - shfl_xor(16,32) reduce -> relu(agg) f16 to d_ws.
// Kernel B: 256 blocks x 16 batches: out = relu_agg @ Wagg^T + bagg.

typedef _Float16 half_t;
typedef half_t f16x4 __attribute__((ext_vector_type(4)));
typedef float f32x4 __attribute__((ext_vector_type(4)));

__global__ __launch_bounds__(256, 4) void agg_kernel(
    const float* __restrict__ x,     // [4096,257,16]
    const float* __restrict__ Wfc,   // [128,16]
    const float* __restrict__ bfc,   // [128]
    half_t* __restrict__ agg_out)    // [4096,128] f16
{
    const int t    = threadIdx.x;
    const int lane = t & 63;
    const int wv   = t >> 6;
    const int b    = blockIdx.x * 4 + wv;
    const int lr   = lane & 15;   // row-in-tile (A) / col-in-tile (B,D)
    const int lc   = lane >> 4;   // k-quarter / D reg-group

    __shared__ float wls[4][256];

    const float* xb = x + (size_t)b * (257 * 16);

    // ---- issue weight-input loads (4 agents per lane) ----
    float dxv[4], dyv[4], f6[4];
    #pragma unroll
    for (int i = 0; i < 4; ++i) {
        const float* ar = xb + (size_t)(1 + lane + 64 * i) * 16;
        const float2 p = *(const float2*)ar;
        dxv[i] = p.x; dyv[i] = p.y; f6[i] = ar[6];
    }
    const float2 ego = *(const float2*)xb;

    // ---- A-frags: all 16 m-tiles, straight from global, cvt to f16 ----
    f16x4 afr[16];
    #pragma unroll
    for (int tm = 0; tm < 16; ++tm) {
        const float4 av = *(const float4*)(xb + (size_t)(1 + tm * 16 + lr) * 16 + lc * 4);
        afr[tm] = (f16x4){(half_t)av.x, (half_t)av.y, (half_t)av.z, (half_t)av.w};
    }

    // ---- B-frags (Wfc^T) + bias ----
    f16x4 bf[8];
    float cbias[8];
    #pragma unroll
    for (int ct = 0; ct < 8; ++ct) {
        const int col = ct * 16 + lr;
        const float4 v = *(const float4*)(Wfc + col * 16 + lc * 4);
        bf[ct] = (f16x4){(half_t)v.x, (half_t)v.y, (half_t)v.z, (half_t)v.w};
        cbias[ct] = bfc[col];
    }

    // ---- weights: compute, wave-reduce, normalize, stage in LDS ----
    float wq[4];
    float wsum = 0.f;
    #pragma unroll
    for (int i = 0; i < 4; ++i) {
        const float dx = dxv[i] - ego.x, dy = dyv[i] - ego.y;
        float w = 1.0f / (sqrtf(dx * dx + dy * dy) + 1.0f);
        if (f6[i] == 1.0f) w *= 5.0f;
        wq[i] = w; wsum += w;
    }
    #pragma unroll
    for (int off = 32; off > 0; off >>= 1) wsum += __shfl_xor(wsum, off);
    const float inv = 1.0f / (wsum + 1e-10f);
    #pragma unroll
    for (int i = 0; i < 4; ++i) wls[wv][lane + 64 * i] = wq[i] * inv;

    // ---- emb GEMM + relu + weighted row-agg ----
    float pacc[8] = {0.f, 0.f, 0.f, 0.f, 0.f, 0.f, 0.f, 0.f};
    #pragma unroll
    for (int tm = 0; tm < 16; ++tm) {
        const float4 w4 = *(const float4*)(&wls[wv][tm * 16 + lc * 4]);
        #pragma unroll
        for (int ct = 0; ct < 8; ++ct) {
            const f32x4 c = (f32x4){cbias[ct], cbias[ct], cbias[ct], cbias[ct]};
            const f32x4 d = __builtin_amdgcn_mfma_f32_16x16x16f16(afr[tm], bf[ct], c, 0, 0, 0);
            pacc[ct] = fmaf(w4.x, fmaxf(d[0], 0.f), pacc[ct]);
            pacc[ct] = fmaf(w4.y, fmaxf(d[1], 0.f), pacc[ct]);
            pacc[ct] = fmaf(w4.z, fmaxf(d[2], 0.f), pacc[ct]);
            pacc[ct] = fmaf(w4.w, fmaxf(d[3], 0.f), pacc[ct]);
        }
    }

    // ---- reduce across 16-lane groups; lanes 0-15 store ----
    #pragma unroll
    for (int ct = 0; ct < 8; ++ct) {
        float p = pacc[ct];
        p += __shfl_xor(p, 16);
        p += __shfl_xor(p, 32);
        pacc[ct] = p;
    }
    if (lane < 16) {
        #pragma unroll
        for (int ct = 0; ct < 8; ++ct)
            agg_out[(size_t)b * 128 + ct * 16 + lane] = (half_t)fmaxf(pacc[ct], 0.f);
    }
}

__global__ __launch_bounds__(256) void out_kernel(
    const half_t* __restrict__ agg,  // [4096,128] f16 (relu applied)
    const float* __restrict__ Wagg,  // [128,128]
    const float* __restrict__ bagg,  // [128]
    float* __restrict__ out)         // [4096,128]
{
    const int blk  = blockIdx.x;     // 16 batches per block
    const int t    = threadIdx.x;
    const int lane = t & 63;
    const int wv   = t >> 6;
    const int lr   = lane & 15;
    const int lc   = lane >> 4;
    const int row0 = blk * 16;

    f32x4 acc[2];
    #pragma unroll
    for (int ci = 0; ci < 2; ++ci) {
        const int col = (wv * 2 + ci) * 16 + lr;
        const float bb = bagg[col];
        acc[ci] = (f32x4){bb, bb, bb, bb};
    }
    #pragma unroll
    for (int kk = 0; kk < 8; ++kk) {
        const int k0 = kk * 16 + lc * 4;
        const f16x4 a = *(const f16x4*)(agg + (size_t)(row0 + lr) * 128 + k0);
        #pragma unroll
        for (int ci = 0; ci < 2; ++ci) {
            const int col = (wv * 2 + ci) * 16 + lr;
            const float4 v = *(const float4*)(Wagg + col * 128 + k0);
            const f16x4 bfr = (f16x4){(half_t)v.x, (half_t)v.y, (half_t)v.z, (half_t)v.w};
            acc[ci] = __builtin_amdgcn_mfma_f32_16x16x16f16(a, bfr, acc[ci], 0, 0, 0);
        }
    }
    #pragma unroll
    for (int ci = 0; ci < 2; ++ci) {
        const int col = (wv * 2 + ci) * 16 + lr;
        #pragma unroll
        for (int j = 0; j < 4; ++j)
            out[(size_t)(row0 + lc * 4 + j) * 128 + col] = acc[ci][j];
    }
}

extern "C" void kernel_launch(void* const* d_in, const int* in_sizes, int n_in,
                              void* d_out, int out_size, void* d_ws, size_t ws_size,
                              hipStream_t stream) {
    const float* x    = (const float*)d_in[0];
    const float* Wfc  = (const float*)d_in[1];
    const float* bfc  = (const float*)d_in[2];
    const float* Wagg = (const float*)d_in[3];
    const float* bagg = (const float*)d_in[4];
    float* out = (float*)d_out;
    half_t* agg_ws = (half_t*)d_ws;   // 4096*128 f16 = 1 MB

    agg_kernel<<<dim3(1024), dim3(256), 0, stream>>>(x, Wfc, bfc, agg_ws);
    out_kernel<<<dim3(256), dim3(256), 0, stream>>>(agg_ws, Wagg, bagg, out);
}

// Round 4
// 36.064 us; speedup vs baseline: 2.2973x; 1.0225x over previous
//
#include <hip/hip_runtime.h>

// InfluenceEncoder via MFMA f16: B=4096, N=257, D=16, H=128.
// Kernel A: wave-per-batch, barrier-free, software-pipelined.
//   - weights: lane l -> agents {l,l+64,l+128,l+192}; UNNORMALIZED w staged
//     in wave-private LDS slice; normalization deferred to the epilogue
//     (w/S applied as uniform 1/S after the cross-lane reduce).
//   - emb GEMM: 16 m-tiles x 8 col-tiles of mfma_f32_16x16x16_f16.
//     A-tiles pipelined 4-deep from global (float4 coalesced, cvt to f16
//     just-in-time). Bias rides in the MFMA C-operand (cvec, not consumed).
//     relu + weighted row-agg on D regs.
//   - shfl_xor(16,32) reduce, scale by 1/S, relu -> f16 agg to d_ws.
// Kernel B: 256 blocks x 16 batches: out = relu_agg @ Wagg^T + bagg.

typedef _Float16 half_t;
typedef half_t f16x4 __attribute__((ext_vector_type(4)));
typedef float f32x4 __attribute__((ext_vector_type(4)));

__global__ __launch_bounds__(256, 4) void agg_kernel(
    const float* __restrict__ x,     // [4096,257,16]
    const float* __restrict__ Wfc,   // [128,16]
    const float* __restrict__ bfc,   // [128]
    half_t* __restrict__ agg_out)    // [4096,128] f16
{
    const int t    = threadIdx.x;
    const int lane = t & 63;
    const int wv   = t >> 6;
    const int b    = blockIdx.x * 4 + wv;
    const int lr   = lane & 15;   // row-in-tile (A) / col-in-tile (B,D)
    const int lc   = lane >> 4;   // k-quarter / D reg-group

    __shared__ float wls[4][256];

    const float* xb = x + (size_t)b * (257 * 16);

    // ---- weights (unnormalized), staged in wave-private LDS ----
    float wq[4];
    {
        float2 p[4]; float f6[4];
        #pragma unroll
        for (int i = 0; i < 4; ++i) {
            const float* ar = xb + (size_t)(1 + lane + 64 * i) * 16;
            p[i] = *(const float2*)ar;
            f6[i] = ar[6];
        }
        const float2 ego = *(const float2*)xb;
        #pragma unroll
        for (int i = 0; i < 4; ++i) {
            const float dx = p[i].x - ego.x, dy = p[i].y - ego.y;
            float w = 1.0f / (sqrtf(dx * dx + dy * dy) + 1.0f);
            if (f6[i] == 1.0f) w *= 5.0f;
            wq[i] = w;
            wls[wv][lane + 64 * i] = w;
        }
    }

    // ---- B-frags (Wfc^T) + bias vectors ----
    f16x4 bf[8];
    f32x4 cvec[8];
    #pragma unroll
    for (int ct = 0; ct < 8; ++ct) {
        const int col = ct * 16 + lr;
        const float4 v = *(const float4*)(Wfc + col * 16 + lc * 4);
        bf[ct] = (f16x4){(half_t)v.x, (half_t)v.y, (half_t)v.z, (half_t)v.w};
        const float bb = bfc[col];
        cvec[ct] = (f32x4){bb, bb, bb, bb};
    }

    // ---- emb GEMM, 4-deep pipelined A-tiles ----
    float pacc[8] = {0.f, 0.f, 0.f, 0.f, 0.f, 0.f, 0.f, 0.f};
    float4 abuf[4];
    #pragma unroll
    for (int i = 0; i < 4; ++i)
        abuf[i] = *(const float4*)(xb + (size_t)(1 + i * 16 + lr) * 16 + lc * 4);

    #pragma unroll
    for (int tm = 0; tm < 16; ++tm) {
        const float4 av = abuf[tm & 3];
        if (tm < 12)
            abuf[tm & 3] = *(const float4*)(xb + (size_t)(1 + (tm + 4) * 16 + lr) * 16 + lc * 4);
        const f16x4 a = (f16x4){(half_t)av.x, (half_t)av.y, (half_t)av.z, (half_t)av.w};
        const float4 w4 = *(const float4*)(&wls[wv][tm * 16 + lc * 4]);
        #pragma unroll
        for (int ct = 0; ct < 8; ++ct) {
            const f32x4 d = __builtin_amdgcn_mfma_f32_16x16x16f16(a, bf[ct], cvec[ct], 0, 0, 0);
            pacc[ct] = fmaf(w4.x, fmaxf(d[0], 0.f), pacc[ct]);
            pacc[ct] = fmaf(w4.y, fmaxf(d[1], 0.f), pacc[ct]);
            pacc[ct] = fmaf(w4.z, fmaxf(d[2], 0.f), pacc[ct]);
            pacc[ct] = fmaf(w4.w, fmaxf(d[3], 0.f), pacc[ct]);
        }
    }

    // ---- deferred normalization + reduce + store ----
    float wsum = wq[0] + wq[1] + wq[2] + wq[3];
    #pragma unroll
    for (int off = 32; off > 0; off >>= 1) wsum += __shfl_xor(wsum, off);
    const float inv = 1.0f / (wsum + 1e-10f);

    #pragma unroll
    for (int ct = 0; ct < 8; ++ct) {
        float p = pacc[ct];
        p += __shfl_xor(p, 16);
        p += __shfl_xor(p, 32);
        pacc[ct] = p * inv;
    }
    if (lane < 16) {
        #pragma unroll
        for (int ct = 0; ct < 8; ++ct)
            agg_out[(size_t)b * 128 + ct * 16 + lane] = (half_t)fmaxf(pacc[ct], 0.f);
    }
}

__global__ __launch_bounds__(256) void out_kernel(
    const half_t* __restrict__ agg,  // [4096,128] f16 (relu applied)
    const float* __restrict__ Wagg,  // [128,128]
    const float* __restrict__ bagg,  // [128]
    float* __restrict__ out)         // [4096,128]
{
    const int blk  = blockIdx.x;     // 16 batches per block
    const int t    = threadIdx.x;
    const int lane = t & 63;
    const int wv   = t >> 6;
    const int lr   = lane & 15;
    const int lc   = lane >> 4;
    const int row0 = blk * 16;

    f32x4 acc[2];
    #pragma unroll
    for (int ci = 0; ci < 2; ++ci) {
        const int col = (wv * 2 + ci) * 16 + lr;
        const float bb = bagg[col];
        acc[ci] = (f32x4){bb, bb, bb, bb};
    }
    #pragma unroll
    for (int kk = 0; kk < 8; ++kk) {
        const int k0 = kk * 16 + lc * 4;
        const f16x4 a = *(const f16x4*)(agg + (size_t)(row0 + lr) * 128 + k0);
        #pragma unroll
        for (int ci = 0; ci < 2; ++ci) {
            const int col = (wv * 2 + ci) * 16 + lr;
            const float4 v = *(const float4*)(Wagg + col * 128 + k0);
            const f16x4 bfr = (f16x4){(half_t)v.x, (half_t)v.y, (half_t)v.z, (half_t)v.w};
            acc[ci] = __builtin_amdgcn_mfma_f32_16x16x16f16(a, bfr, acc[ci], 0, 0, 0);
        }
    }
    #pragma unroll
    for (int ci = 0; ci < 2; ++ci) {
        const int col = (wv * 2 + ci) * 16 + lr;
        #pragma unroll
        for (int j = 0; j < 4; ++j)
            out[(size_t)(row0 + lc * 4 + j) * 128 + col] = acc[ci][j];
    }
}

extern "C" void kernel_launch(void* const* d_in, const int* in_sizes, int n_in,
                              void* d_out, int out_size, void* d_ws, size_t ws_size,
                              hipStream_t stream) {
    const float* x    = (const float*)d_in[0];
    const float* Wfc  = (const float*)d_in[1];
    const float* bfc  = (const float*)d_in[2];
    const float* Wagg = (const float*)d_in[3];
    const float* bagg = (const float*)d_in[4];
    float* out = (float*)d_out;
    half_t* agg_ws = (half_t*)d_ws;   // 4096*128 f16 = 1 MB

    agg_kernel<<<dim3(1024), dim3(256), 0, stream>>>(x, Wfc, bfc, agg_ws);
    out_kernel<<<dim3(256), dim3(256), 0, stream>>>(agg_ws, Wagg, bagg, out);
}

// Round 5
// 30.471 us; speedup vs baseline: 2.7189x; 1.1835x over previous
//
#include <hip/hip_runtime.h>

// InfluenceEncoder: B=4096, N=257, D=16, H=128.
// Kernel A: HALF-batch per wave (8192 waves). 32x32x16 f16 MFMA (fast path).
//   Wave W: batch b=W>>1, half hf=W&1 (128 agents). 4 m-tiles x 4 col-tiles.
//   - A-tiles: lane reads row (lane&31), k-octet (lane>>5) -> 2 float4 (wave
//     covers 2KB contiguous). Weights computed by lo-half lanes FROM THESE
//     REGS (x,y,f6 are k=0,1,6) -> wave-private LDS slice, barrier-free.
//   - relu-bias fold: relu(e+b) = max(e,-b)+b; postproc = fmax+fmaf only.
//   - outputs: unnormalized partial pacc (f32) + partial wsum to d_ws.
// Kernel B: 2048 waves; job = (batch-tile of 16, col-tile of 16).
//   Renorm+bias+relu+cvt fused into A-frag path; 4x mfma_f32_16x16x32_f16
//   over K=128 vs Wagg^T; += bagg; fp32 out.

typedef _Float16 half_t;
typedef half_t f16x8 __attribute__((ext_vector_type(8)));
typedef float f32x4 __attribute__((ext_vector_type(4)));
typedef float f32x16 __attribute__((ext_vector_type(16)));

__global__ __launch_bounds__(256, 5) void agg_kernel(
    const float* __restrict__ x,     // [4096,257,16]
    const float* __restrict__ Wfc,   // [128,16]
    const float* __restrict__ bfc,   // [128]
    float* __restrict__ p_ws,        // [4096][2][128] unnormalized partials
    float* __restrict__ s_ws)        // [4096][2] partial weight sums
{
    const int t    = threadIdx.x;
    const int lane = t & 63;
    const int wv   = t >> 6;
    const int W    = blockIdx.x * 4 + wv;
    const int b    = W >> 1;
    const int hf   = W & 1;
    const int lm   = lane & 31;   // row-in-tile (A) / col-in-tile (B,D)
    const int hi   = lane >> 5;   // k-octet

    __shared__ float wls[4][128];

    const float* xb = x + (size_t)b * (257 * 16);
    const int row0 = 1 + hf * 128;

    // ---- A-tile loads: 4 tiles of 32 rows; lane -> row lm, k [hi*8, +8) ----
    float4 a0[4], a1[4];
    #pragma unroll
    for (int tm = 0; tm < 4; ++tm) {
        const float* rp = xb + (size_t)(row0 + tm * 32 + lm) * 16 + hi * 8;
        a0[tm] = *(const float4*)rp;
        a1[tm] = *(const float4*)(rp + 4);
    }

    // ---- B-frags: B[k=hi*8+j][col=ct*32+lm] = Wfc[ct*32+lm][hi*8+j] ----
    f16x8 bfr[4];
    #pragma unroll
    for (int ct = 0; ct < 4; ++ct) {
        const float* wp = Wfc + (size_t)(ct * 32 + lm) * 16 + hi * 8;
        const float4 w0 = *(const float4*)wp;
        const float4 w1 = *(const float4*)(wp + 4);
        bfr[ct] = (f16x8){(half_t)w0.x, (half_t)w0.y, (half_t)w0.z, (half_t)w0.w,
                          (half_t)w1.x, (half_t)w1.y, (half_t)w1.z, (half_t)w1.w};
    }

    float nb[4];   // -bias for relu-fold
    #pragma unroll
    for (int ct = 0; ct < 4; ++ct) nb[ct] = -bfc[ct * 32 + lm];

    const float2 ego = *(const float2*)xb;

    // ---- weights from A regs (lo lanes hold k=0..7: x,y at 0,1; f6 at 6) ----
    float wsum = 0.f;
    if (hi == 0) {
        #pragma unroll
        for (int tm = 0; tm < 4; ++tm) {
            const float dx = a0[tm].x - ego.x;
            const float dy = a0[tm].y - ego.y;
            float w = 1.0f / (sqrtf(dx * dx + dy * dy) + 1.0f);
            if (a1[tm].z == 1.0f) w *= 5.0f;   // k=6
            wls[wv][tm * 32 + lm] = w;
            wsum += w;
        }
    }
    #pragma unroll
    for (int off = 32; off > 0; off >>= 1) wsum += __shfl_xor(wsum, off);

    // ---- cvt A to f16 frags ----
    f16x8 afr[4];
    #pragma unroll
    for (int tm = 0; tm < 4; ++tm)
        afr[tm] = (f16x8){(half_t)a0[tm].x, (half_t)a0[tm].y, (half_t)a0[tm].z, (half_t)a0[tm].w,
                          (half_t)a1[tm].x, (half_t)a1[tm].y, (half_t)a1[tm].z, (half_t)a1[tm].w};

    // ---- MFMA + fold-relu weighted row-agg ----
    // D layout: col=lane&31, row=(r&3)+8*(r>>2)+4*hi
    float pacc[4] = {0.f, 0.f, 0.f, 0.f};
    #pragma unroll
    for (int tm = 0; tm < 4; ++tm) {
        float4 w4[4];
        #pragma unroll
        for (int q = 0; q < 4; ++q)
            w4[q] = *(const float4*)(&wls[wv][tm * 32 + q * 8 + hi * 4]);
        #pragma unroll
        for (int ct = 0; ct < 4; ++ct) {
            f32x16 zc = {};
            const f32x16 d = __builtin_amdgcn_mfma_f32_32x32x16_f16(afr[tm], bfr[ct], zc, 0, 0, 0);
            #pragma unroll
            for (int r = 0; r < 16; ++r)
                pacc[ct] = fmaf(w4[r >> 2][r & 3], fmaxf(d[r], nb[ct]), pacc[ct]);
        }
    }

    // ---- combine k-octet halves, store partials ----
    #pragma unroll
    for (int ct = 0; ct < 4; ++ct) pacc[ct] += __shfl_xor(pacc[ct], 32);
    if (hi == 0) {
        float* pp = p_ws + ((size_t)b * 2 + hf) * 128;
        #pragma unroll
        for (int ct = 0; ct < 4; ++ct) pp[ct * 32 + lm] = pacc[ct];
        if (lane == 0) s_ws[b * 2 + hf] = wsum;
    }
}

__global__ __launch_bounds__(256, 4) void out_kernel(
    const float* __restrict__ p_ws,  // [4096][2][128]
    const float* __restrict__ s_ws,  // [4096][2]
    const float* __restrict__ bfc,   // [128]
    const float* __restrict__ Wagg,  // [128,128]
    const float* __restrict__ bagg,  // [128]
    float* __restrict__ out)         // [4096,128]
{
    const int t    = threadIdx.x;
    const int lane = t & 63;
    const int wv   = t >> 6;
    const int j    = blockIdx.x * 4 + wv;  // 0..2047
    const int mt   = j >> 3;               // batch tile (16 rows)
    const int ct   = j & 7;                // col tile (16 cols)
    const int lr   = lane & 15;
    const int lq   = lane >> 4;

    const int brow = mt * 16 + lr;
    const float2 s2 = *(const float2*)(s_ws + brow * 2);
    const float inv = 1.0f / (s2.x + s2.y + 1e-10f);

    const int col = ct * 16 + lr;
    const float bb = bagg[col];
    f32x4 acc = (f32x4){bb, bb, bb, bb};

    const float* pbase = p_ws + (size_t)brow * 256;
    const float* wrow  = Wagg + (size_t)col * 128;

    #pragma unroll
    for (int kk = 0; kk < 4; ++kk) {
        const int k0 = kk * 32 + lq * 8;
        const float4 p00 = *(const float4*)(pbase + k0);
        const float4 p01 = *(const float4*)(pbase + k0 + 4);
        const float4 p10 = *(const float4*)(pbase + 128 + k0);
        const float4 p11 = *(const float4*)(pbase + 128 + k0 + 4);
        const float4 bf0 = *(const float4*)(bfc + k0);
        const float4 bf1 = *(const float4*)(bfc + k0 + 4);
        // e = relu((p0+p1)*inv + bfc)  (renorm + bias + relu fused)
        const f16x8 afr = (f16x8){
            (half_t)fmaxf(fmaf(p00.x + p10.x, inv, bf0.x), 0.f),
            (half_t)fmaxf(fmaf(p00.y + p10.y, inv, bf0.y), 0.f),
            (half_t)fmaxf(fmaf(p00.z + p10.z, inv, bf0.z), 0.f),
            (half_t)fmaxf(fmaf(p00.w + p10.w, inv, bf0.w), 0.f),
            (half_t)fmaxf(fmaf(p01.x + p11.x, inv, bf1.x), 0.f),
            (half_t)fmaxf(fmaf(p01.y + p11.y, inv, bf1.y), 0.f),
            (half_t)fmaxf(fmaf(p01.z + p11.z, inv, bf1.z), 0.f),
            (half_t)fmaxf(fmaf(p01.w + p11.w, inv, bf1.w), 0.f)};
        const float4 wg0 = *(const float4*)(wrow + k0);
        const float4 wg1 = *(const float4*)(wrow + k0 + 4);
        const f16x8 bfr = (f16x8){(half_t)wg0.x, (half_t)wg0.y, (half_t)wg0.z, (half_t)wg0.w,
                                  (half_t)wg1.x, (half_t)wg1.y, (half_t)wg1.z, (half_t)wg1.w};
        acc = __builtin_amdgcn_mfma_f32_16x16x32_f16(afr, bfr, acc, 0, 0, 0);
    }

    // D: col=lane&15, row=lq*4+jj
    #pragma unroll
    for (int jj = 0; jj < 4; ++jj)
        out[(size_t)(mt * 16 + lq * 4 + jj) * 128 + col] = acc[jj];
}

extern "C" void kernel_launch(void* const* d_in, const int* in_sizes, int n_in,
                              void* d_out, int out_size, void* d_ws, size_t ws_size,
                              hipStream_t stream) {
    const float* x    = (const float*)d_in[0];
    const float* Wfc  = (const float*)d_in[1];
    const float* bfc  = (const float*)d_in[2];
    const float* Wagg = (const float*)d_in[3];
    const float* bagg = (const float*)d_in[4];
    float* out = (float*)d_out;

    float* p_ws = (float*)d_ws;                 // 4096*256 f32 = 4 MB
    float* s_ws = p_ws + (size_t)4096 * 256;    // 4096*2 f32

    agg_kernel<<<dim3(2048), dim3(256), 0, stream>>>(x, Wfc, bfc, p_ws, s_ws);
    out_kernel<<<dim3(512), dim3(256), 0, stream>>>(p_ws, s_ws, bfc, Wagg, bagg, out);
}